// Round 10
// baseline (1149.275 us; speedup 1.0000x reference)
//
#include <hip/hip_runtime.h>
#include <hip/hip_bf16.h>

// Bidirectional GRU (T=512,B=512,E=128,H=64) + word attention, f32.
// Pipeline: xgv (vocab-folded input projection) -> gru_scan (persistent,
// register-resident weights, readlane h-broadcast) -> attn scores (wave-
// persistent) -> fused softmax-over-T + weighted sum.
//
// [r10 history: r1=1525 (scan scratch-spill). r5=1240 (scan hand-unroll +
//  waves_per_eu(1,1): 653->~370us). r8=1067 (attn wave-persistent rewrite
//  601->418us, but VGPR=140: allocator reloads ~120 weights/row from L2).
//  r9: PIN pins = ZERO effect (VGPR 140, dur 415 -- allocator ignores pins;
//  ~945 VALU instr/row vs 330 ideal, AND 52% idle at 1 wave/SIMD).
//  r10 change (attn only, single variable): stop fighting the allocator --
//  accept VGPR~140 and hide the reload latency with TLP. launch_bounds(64,2)
//  -> 2 waves/SIMD co-resident (2048-wave grid = exactly 2/SIMD).
//  Predict: attn 415 -> ~210-250us, VALUBusy 48->80-95%, Occ 12->24%;
//  total 1071 -> ~860-900us.]

#define T_LEN 512
#define B_SZ  512
#define E_DIM 128
#define H_DIM 64
#define G3    192          // 3*H
#define V_SZ  50001
#define TWOH  128

// workspace offsets (in floats)
#define XGV_SZ (V_SZ * G3)                 // 9,600,192
#define HS_SZ  (T_LEN * B_SZ * H_DIM)      // 16,777,216
#define OFF_XGV_F 0
#define OFF_XGV_B (XGV_SZ)
#define OFF_HS_F  (2 * XGV_SZ)
#define OFF_HS_B  (2 * XGV_SZ + HS_SZ)
#define OFF_SC    (2 * XGV_SZ + 2 * HS_SZ) // scores [B][T]
// total ws: 53,016,960 floats = 212 MB

__device__ __forceinline__ float sigm(float x) {
    return 1.0f / (1.0f + __expf(-x));
}
__device__ __forceinline__ float tanh_fast(float x) {
    float ax = fminf(fabsf(x), 15.0f);
    float e  = __expf(2.0f * ax);
    float r  = 1.0f - 2.0f / (e + 1.0f);
    return copysignf(r, x);
}
__device__ __forceinline__ float rdlane_f(float v, int l) {
    return __uint_as_float(__builtin_amdgcn_readlane(__float_as_uint(v), l));
}
// Opaque register pin (r9 result: does NOT force residency on this
// toolchain; kept only in gru_scan to leave that kernel byte-identical).
#define PIN(x) asm volatile("" : "+v"(x))

// ---------------------------------------------------------------------------
// Kernel A: xgv[v][g] = b_ih[g] + sum_e embed[v][e] * w_ih[g][e]  (per dir)
// block 256 = 4 waves; block covers 64 vocab rows; lane j owns gate columns
// {j, 64+j, 128+j}; wave s covers rows s+4k.
// ---------------------------------------------------------------------------
__global__ __launch_bounds__(256, 2) void xgv_kernel(
    const float* __restrict__ embed,
    const float* __restrict__ w_ih_f, const float* __restrict__ b_ih_f,
    const float* __restrict__ w_ih_b, const float* __restrict__ b_ih_b,
    float* __restrict__ ws)
{
    const int dir = blockIdx.y;
    const float* __restrict__ w_ih = dir ? w_ih_b : w_ih_f;
    const float* __restrict__ b_ih = dir ? b_ih_b : b_ih_f;
    float* __restrict__ xgv = ws + (dir ? OFF_XGV_B : OFF_XGV_F);
    const int v0 = blockIdx.x * 64;
    const int j  = threadIdx.x & 63;
    const int s  = threadIdx.x >> 6;

    float accr[16], accz[16], accn[16];
#pragma unroll
    for (int k = 0; k < 16; ++k) { accr[k] = 0.f; accz[k] = 0.f; accn[k] = 0.f; }

#pragma unroll 1
    for (int ec = 0; ec < 4; ++ec) {
        float wrc[32], wzc[32], wnc[32];
        const float4* wpr = (const float4*)(w_ih + (j      ) * 128 + ec * 32);
        const float4* wpz = (const float4*)(w_ih + (64  + j) * 128 + ec * 32);
        const float4* wpn = (const float4*)(w_ih + (128 + j) * 128 + ec * 32);
#pragma unroll
        for (int i = 0; i < 8; ++i) {
            float4 a = wpr[i];
            wrc[4*i+0] = a.x; wrc[4*i+1] = a.y; wrc[4*i+2] = a.z; wrc[4*i+3] = a.w;
            float4 b = wpz[i];
            wzc[4*i+0] = b.x; wzc[4*i+1] = b.y; wzc[4*i+2] = b.z; wzc[4*i+3] = b.w;
            float4 c = wpn[i];
            wnc[4*i+0] = c.x; wnc[4*i+1] = c.y; wnc[4*i+2] = c.z; wnc[4*i+3] = c.w;
        }
#pragma unroll
        for (int k = 0; k < 16; ++k) {
            const int v = v0 + s + 4 * k;
            if (v < V_SZ) {
                const float4* ep = (const float4*)(embed + v * 128 + ec * 32);
#pragma unroll
                for (int i = 0; i < 8; ++i) {
                    float4 e4 = ep[i];
                    accr[k] = fmaf(e4.x, wrc[4*i+0], accr[k]);
                    accr[k] = fmaf(e4.y, wrc[4*i+1], accr[k]);
                    accr[k] = fmaf(e4.z, wrc[4*i+2], accr[k]);
                    accr[k] = fmaf(e4.w, wrc[4*i+3], accr[k]);
                    accz[k] = fmaf(e4.x, wzc[4*i+0], accz[k]);
                    accz[k] = fmaf(e4.y, wzc[4*i+1], accz[k]);
                    accz[k] = fmaf(e4.z, wzc[4*i+2], accz[k]);
                    accz[k] = fmaf(e4.w, wzc[4*i+3], accz[k]);
                    accn[k] = fmaf(e4.x, wnc[4*i+0], accn[k]);
                    accn[k] = fmaf(e4.y, wnc[4*i+1], accn[k]);
                    accn[k] = fmaf(e4.z, wnc[4*i+2], accn[k]);
                    accn[k] = fmaf(e4.w, wnc[4*i+3], accn[k]);
                }
            }
        }
    }
    const float br = b_ih[j], bz = b_ih[64 + j], bn = b_ih[128 + j];
#pragma unroll
    for (int k = 0; k < 16; ++k) {
        const int v = v0 + s + 4 * k;
        if (v < V_SZ) {
            float* o = xgv + (size_t)v * G3;
            o[j]        = accr[k] + br;
            o[64 + j]   = accz[k] + bz;
            o[128 + j]  = accn[k] + bn;
        }
    }
}

// ---------------------------------------------------------------------------
// Kernel B: the sequential GRU scan. 1 wave = 1 (batch row, direction) for
// all T steps. Unchanged from r9 (grid is fixed at 1 wave/SIMD; will be
// re-attacked from its own counters once it tops the profile).
// ---------------------------------------------------------------------------
#define GRU_STEP(hh)                                        \
    {                                                       \
        const float h0v = rdlane_f(h, (hh));                \
        const float h1v = rdlane_f(h, (hh) + 1);            \
        ar0 = fmaf(h0v, wr[(hh)],     ar0);                 \
        az0 = fmaf(h0v, wz[(hh)],     az0);                 \
        an0 = fmaf(h0v, wn[(hh)],     an0);                 \
        ar1 = fmaf(h1v, wr[(hh) + 1], ar1);                 \
        az1 = fmaf(h1v, wz[(hh) + 1], az1);                 \
        an1 = fmaf(h1v, wn[(hh) + 1], an1);                 \
    }

__global__ __launch_bounds__(64) __attribute__((amdgpu_waves_per_eu(1, 1)))
void gru_scan_kernel(
    const int*   __restrict__ input,
    const float* __restrict__ h0,
    const float* __restrict__ w_hh_f, const float* __restrict__ b_hh_f,
    const float* __restrict__ w_hh_b, const float* __restrict__ b_hh_b,
    float* __restrict__ ws, float* __restrict__ d_out)
{
    const int dir = blockIdx.y;
    const int j   = threadIdx.x & 63;
    const int b   = blockIdx.x;

    const float* __restrict__ w_hh = dir ? w_hh_b : w_hh_f;
    const float* __restrict__ b_hh = dir ? b_hh_b : b_hh_f;
    const float* __restrict__ xgv  = ws + (dir ? OFF_XGV_B : OFF_XGV_F);
    float* __restrict__ hs = ws + (dir ? OFF_HS_B : OFF_HS_F);

    float wr[64], wz[64], wn[64];
    {
        const float4* pr = (const float4*)(w_hh + (j      ) * 64);
        const float4* pz = (const float4*)(w_hh + (64  + j) * 64);
        const float4* pn = (const float4*)(w_hh + (128 + j) * 64);
#pragma unroll
        for (int i = 0; i < 16; ++i) {
            float4 a = pr[i];
            wr[4*i+0] = a.x; wr[4*i+1] = a.y; wr[4*i+2] = a.z; wr[4*i+3] = a.w;
            float4 bq = pz[i];
            wz[4*i+0] = bq.x; wz[4*i+1] = bq.y; wz[4*i+2] = bq.z; wz[4*i+3] = bq.w;
            float4 c = pn[i];
            wn[4*i+0] = c.x; wn[4*i+1] = c.y; wn[4*i+2] = c.z; wn[4*i+3] = c.w;
        }
    }
#pragma unroll
    for (int i = 0; i < 64; ++i) { PIN(wr[i]); PIN(wz[i]); PIN(wn[i]); }

    const float br = b_hh[j], bz = b_hh[64 + j], bn = b_hh[128 + j];

    float h = h0[dir * (B_SZ * H_DIM) + b * H_DIM + j];

    int tok0 = __builtin_amdgcn_readfirstlane(input[(dir ? (T_LEN - 1) : 0) * B_SZ + b]);
    int tok_next_raw = input[(dir ? (T_LEN - 2) : 1) * B_SZ + b];
    float xr = xgv[(size_t)tok0 * G3 + j];
    float xz = xgv[(size_t)tok0 * G3 + 64 + j];
    float xn = xgv[(size_t)tok0 * G3 + 128 + j];

    for (int t = 0; t < T_LEN; ++t) {
        int tok_pf_raw = 0;
        if (t + 2 < T_LEN) {
            const int te2 = dir ? (T_LEN - 3 - t) : (t + 2);
            tok_pf_raw = input[te2 * B_SZ + b];
        }
        float nxr = 0.f, nxz = 0.f, nxn = 0.f;
        if (t + 1 < T_LEN) {
            const int tn = __builtin_amdgcn_readfirstlane(tok_next_raw);
            nxr = xgv[(size_t)tn * G3 + j];
            nxz = xgv[(size_t)tn * G3 + 64 + j];
            nxn = xgv[(size_t)tn * G3 + 128 + j];
        }

        float ar0 = br,  az0 = bz,  an0 = bn;
        float ar1 = 0.f, az1 = 0.f, an1 = 0.f;
        GRU_STEP(0)  GRU_STEP(2)  GRU_STEP(4)  GRU_STEP(6)
        GRU_STEP(8)  GRU_STEP(10) GRU_STEP(12) GRU_STEP(14)
        GRU_STEP(16) GRU_STEP(18) GRU_STEP(20) GRU_STEP(22)
        GRU_STEP(24) GRU_STEP(26) GRU_STEP(28) GRU_STEP(30)
        GRU_STEP(32) GRU_STEP(34) GRU_STEP(36) GRU_STEP(38)
        GRU_STEP(40) GRU_STEP(42) GRU_STEP(44) GRU_STEP(46)
        GRU_STEP(48) GRU_STEP(50) GRU_STEP(52) GRU_STEP(54)
        GRU_STEP(56) GRU_STEP(58) GRU_STEP(60) GRU_STEP(62)
        const float hr = ar0 + ar1;
        const float hz = az0 + az1;
        const float hn = an0 + an1;

        const float rg = sigm(xr + hr);
        const float zg = sigm(xz + hz);
        const float ng = tanh_fast(xn + rg * hn);
        h = (1.0f - zg) * ng + zg * h;

        const int te = dir ? (T_LEN - 1 - t) : t;
        hs[(size_t)te * (B_SZ * H_DIM) + b * H_DIM + j] = h;

        xr = nxr; xz = nxz; xn = nxn;
        tok_next_raw = tok_pf_raw;
    }
    d_out[B_SZ * TWOH + dir * (B_SZ * H_DIM) + b * H_DIM + j] = h;
}

// ---------------------------------------------------------------------------
// Kernel C: scores[b][t] = sum_k tanh(ht.W[:,k]+bias[k])*cw[k].
// Wave-persistent, lane l owns columns {l,64+l}. r10: allocator holds ~140
// VGPR regardless (r8/r9) and reloads the rest from L2 per row -- so run
// 2 waves/SIMD (launch_bounds(64,2), grid 2048 = exactly 2/SIMD) to hide
// the reload latency under the other wave's FMA stream. No waves_per_eu pin,
// no PIN (both proven ineffective).
// ---------------------------------------------------------------------------
#define ATTN_F(hh)                                          \
    {                                                       \
        const float f = rdlane_f(hf, (hh));                 \
        uA = fmaf(f, wA[(hh)], uA);                         \
        uB = fmaf(f, wB[(hh)], uB);                         \
    }
#define ATTN_B(hh)                                          \
    {                                                       \
        const float g = rdlane_f(hb, (hh));                 \
        uA = fmaf(g, wA[64 + (hh)], uA);                    \
        uB = fmaf(g, wB[64 + (hh)], uB);                    \
    }

__global__ __launch_bounds__(64, 2)
void attn_scores_kernel(
    const float* __restrict__ word_weight, const float* __restrict__ word_bias,
    const float* __restrict__ context_weight, float* __restrict__ ws)
{
    const int l = threadIdx.x & 63;
    const float* __restrict__ hs_f = ws + OFF_HS_F;
    const float* __restrict__ hs_b = ws + OFF_HS_B;
    float* __restrict__ sc = ws + OFF_SC;

    // lane l holds W[:,l] and W[:,64+l] (as many as the allocator keeps)
    float wA[128], wB[128];
#pragma unroll
    for (int h = 0; h < 128; ++h) {
        wA[h] = word_weight[h * 128 + l];
        wB[h] = word_weight[h * 128 + 64 + l];
    }
    const float bA = word_bias[l],       bB = word_bias[64 + l];
    const float cA = context_weight[l],  cB = context_weight[64 + l];

    const int r0 = blockIdx.x * 128;    // 128 rows per block; row r=(t<<9)|b

    // 2-deep software pipeline on the row loads (hf=ht[0:64], hb=ht[64:128])
    float hf0, hb0, hf1, hb1;
    {
        const int ta = r0 >> 9, ba = r0 & 511;
        hf0 = hs_f[(size_t)ta * (B_SZ * H_DIM) + ba * H_DIM + l];
        hb0 = hs_b[(size_t)ta * (B_SZ * H_DIM) + ba * H_DIM + l];
        const int rb = r0 + 1;
        const int tb = rb >> 9, bb = rb & 511;
        hf1 = hs_f[(size_t)tb * (B_SZ * H_DIM) + bb * H_DIM + l];
        hb1 = hs_b[(size_t)tb * (B_SZ * H_DIM) + bb * H_DIM + l];
    }

    for (int i = 0; i < 128; ++i) {
        const int r = r0 + i;
        const int t = r >> 9, b = r & 511;

        // prefetch row i+2 (clamped; duplicate loads at the tail are unused)
        float nhf, nhb;
        {
            const int rp = r0 + ((i + 2 < 128) ? (i + 2) : 127);
            const int tp = rp >> 9, bp = rp & 511;
            nhf = hs_f[(size_t)tp * (B_SZ * H_DIM) + bp * H_DIM + l];
            nhb = hs_b[(size_t)tp * (B_SZ * H_DIM) + bp * H_DIM + l];
        }

        const float hf = hf0, hb = hb0;
        float uA = bA, uB = bB;
        ATTN_F(0)  ATTN_F(1)  ATTN_F(2)  ATTN_F(3)  ATTN_F(4)  ATTN_F(5)  ATTN_F(6)  ATTN_F(7)
        ATTN_F(8)  ATTN_F(9)  ATTN_F(10) ATTN_F(11) ATTN_F(12) ATTN_F(13) ATTN_F(14) ATTN_F(15)
        ATTN_F(16) ATTN_F(17) ATTN_F(18) ATTN_F(19) ATTN_F(20) ATTN_F(21) ATTN_F(22) ATTN_F(23)
        ATTN_F(24) ATTN_F(25) ATTN_F(26) ATTN_F(27) ATTN_F(28) ATTN_F(29) ATTN_F(30) ATTN_F(31)
        ATTN_F(32) ATTN_F(33) ATTN_F(34) ATTN_F(35) ATTN_F(36) ATTN_F(37) ATTN_F(38) ATTN_F(39)
        ATTN_F(40) ATTN_F(41) ATTN_F(42) ATTN_F(43) ATTN_F(44) ATTN_F(45) ATTN_F(46) ATTN_F(47)
        ATTN_F(48) ATTN_F(49) ATTN_F(50) ATTN_F(51) ATTN_F(52) ATTN_F(53) ATTN_F(54) ATTN_F(55)
        ATTN_F(56) ATTN_F(57) ATTN_F(58) ATTN_F(59) ATTN_F(60) ATTN_F(61) ATTN_F(62) ATTN_F(63)
        ATTN_B(0)  ATTN_B(1)  ATTN_B(2)  ATTN_B(3)  ATTN_B(4)  ATTN_B(5)  ATTN_B(6)  ATTN_B(7)
        ATTN_B(8)  ATTN_B(9)  ATTN_B(10) ATTN_B(11) ATTN_B(12) ATTN_B(13) ATTN_B(14) ATTN_B(15)
        ATTN_B(16) ATTN_B(17) ATTN_B(18) ATTN_B(19) ATTN_B(20) ATTN_B(21) ATTN_B(22) ATTN_B(23)
        ATTN_B(24) ATTN_B(25) ATTN_B(26) ATTN_B(27) ATTN_B(28) ATTN_B(29) ATTN_B(30) ATTN_B(31)
        ATTN_B(32) ATTN_B(33) ATTN_B(34) ATTN_B(35) ATTN_B(36) ATTN_B(37) ATTN_B(38) ATTN_B(39)
        ATTN_B(40) ATTN_B(41) ATTN_B(42) ATTN_B(43) ATTN_B(44) ATTN_B(45) ATTN_B(46) ATTN_B(47)
        ATTN_B(48) ATTN_B(49) ATTN_B(50) ATTN_B(51) ATTN_B(52) ATTN_B(53) ATTN_B(54) ATTN_B(55)
        ATTN_B(56) ATTN_B(57) ATTN_B(58) ATTN_B(59) ATTN_B(60) ATTN_B(61) ATTN_B(62) ATTN_B(63)

        float s = tanh_fast(uA) * cA + tanh_fast(uB) * cB;
#pragma unroll
        for (int off = 32; off >= 1; off >>= 1) s += __shfl_xor(s, off);
        if (l == 0) sc[b * 512 + t] = s;

        hf0 = hf1; hb0 = hb1;
        hf1 = nhf; hb1 = nhb;
    }
}

// ---------------------------------------------------------------------------
// Kernel D (fused): per batch row b — softmax over t of sc[b][:], then
// s_i[b][k] = sum_t a[t] * ht[t][b][k].  Block 512 threads = 8 waves.
// ---------------------------------------------------------------------------
__global__ __launch_bounds__(512, 2) void softmax_wsum_kernel(
    const float* __restrict__ ws_c, float* __restrict__ d_out)
{
    const float* __restrict__ hs_f = ws_c + OFF_HS_F;
    const float* __restrict__ hs_b = ws_c + OFF_HS_B;
    const float* __restrict__ sc   = ws_c + OFF_SC;
    const int b   = blockIdx.x;
    const int tid = threadIdx.x;

    __shared__ float red[8];
    __shared__ float sa[T_LEN];
    __shared__ float psum[4][TWOH];

    // ---- phase 1: softmax over t ----
    {
        const int t = tid;
        const int w = t >> 6;
        float v = sc[b * 512 + t];

        float m = v;
#pragma unroll
        for (int off = 32; off >= 1; off >>= 1) m = fmaxf(m, __shfl_xor(m, off));
        if ((t & 63) == 0) red[w] = m;
        __syncthreads();
        float mm = red[0];
#pragma unroll
        for (int i = 1; i < 8; ++i) mm = fmaxf(mm, red[i]);
        __syncthreads();

        const float e = __expf(v - mm);
        float ssum = e;
#pragma unroll
        for (int off = 32; off >= 1; off >>= 1) ssum += __shfl_xor(ssum, off);
        if ((t & 63) == 0) red[w] = ssum;
        __syncthreads();
        float tot = 0.f;
#pragma unroll
        for (int i = 0; i < 8; ++i) tot += red[i];

        sa[t] = e / tot;
    }
    __syncthreads();

    // ---- phase 2: weighted sum over t ----
    {
        const int k = tid & 127;
        const int c = tid >> 7;             // t-chunk 0..3
        const float* __restrict__ src =
            ((k < 64) ? hs_f : hs_b) + (k & 63) + b * H_DIM;
        const int t0 = c * 128;

        float acc = 0.f, acc2 = 0.f;
#pragma unroll 8
        for (int t = 0; t < 128; t += 2) {
            acc  = fmaf(sa[t0 + t],     src[(size_t)(t0 + t)     * (B_SZ * H_DIM)], acc);
            acc2 = fmaf(sa[t0 + t + 1], src[(size_t)(t0 + t + 1) * (B_SZ * H_DIM)], acc2);
        }
        psum[c][k] = acc + acc2;
    }
    __syncthreads();
    if (tid < TWOH) {
        d_out[b * TWOH + tid] =
            (psum[0][tid] + psum[1][tid]) + (psum[2][tid] + psum[3][tid]);
    }
}

// ---------------------------------------------------------------------------
extern "C" void kernel_launch(void* const* d_in, const int* in_sizes, int n_in,
                              void* d_out, int out_size, void* d_ws, size_t ws_size,
                              hipStream_t stream)
{
    const int*   input  = (const int*)  d_in[0];
    const float* hidden = (const float*)d_in[1];
    const float* embed  = (const float*)d_in[2];
    const float* word_w = (const float*)d_in[3];
    const float* word_b = (const float*)d_in[4];
    const float* ctx_w  = (const float*)d_in[5];
    const float* w_ih_f = (const float*)d_in[6];
    const float* w_hh_f = (const float*)d_in[7];
    const float* b_ih_f = (const float*)d_in[8];
    const float* b_hh_f = (const float*)d_in[9];
    const float* w_ih_b = (const float*)d_in[10];
    const float* w_hh_b = (const float*)d_in[11];
    const float* b_ih_b = (const float*)d_in[12];
    const float* b_hh_b = (const float*)d_in[13];
    float* ws  = (float*)d_ws;
    float* out = (float*)d_out;

    // A: vocab-folded input projection, both directions
    xgv_kernel<<<dim3((V_SZ + 63) / 64, 2), 256, 0, stream>>>(
        embed, w_ih_f, b_ih_f, w_ih_b, b_ih_b, ws);
    // B: sequential scan, 1 wave per (row, dir)
    gru_scan_kernel<<<dim3(B_SZ, 2), 64, 0, stream>>>(
        input, hidden, w_hh_f, b_hh_f, w_hh_b, b_hh_b, ws, out);
    // C: attention scores (wave-persistent, 128 rows/block, 2 waves/SIMD)
    attn_scores_kernel<<<(T_LEN * B_SZ) / 128, 64, 0, stream>>>(
        word_w, word_b, ctx_w, ws);
    // D: fused softmax over time + weighted sum -> s_i
    softmax_wsum_kernel<<<B_SZ, 512, 0, stream>>>(ws, out);
}

// Round 11
// 797.559 us; speedup vs baseline: 1.4410x; 1.4410x over previous
//
#include <hip/hip_runtime.h>
#include <hip/hip_bf16.h>

// Bidirectional GRU (T=512,B=512,E=128,H=64) + word attention, f32.
// Pipeline: xgv (vocab-folded input projection) -> gru_scan (persistent,
// register-resident weights, readlane h-broadcast) -> attn scores (r11:
// scalar-pipe GEMM, weights in SGPRs) -> fused softmax-over-T + weighted sum.
//
// [r11 history: r1=1525 (scan scratch-spill). r5=1240 (scan hand-unroll +
//  waves_per_eu(1,1): 653->~370us -- proven recipe for 1-wave kernels).
//  attn arc: r8 wave-persistent 601->418us but VGPR=140 (allocator remats
//  ~120 weights/row from L2); r9 PIN pins: ZERO effect; r10 launch_bounds
//  (64,2): VGPR capped 128 -> scratch spills (WRITE_SIZE 2->14.6MB), 493us
//  REGRESSION. Conclusion: allocator will not hold 256 loop-carried floats.
//  r11 pivot: restructure scores as scalar-operand GEMM -- W via s_load into
//  SGPRs (v_fmac vdst,s,v legal), 64 rows staged in LDS (pad 129, 2-way=
//  free), lane=row with acc[32] (~50 VGPR), wave=k-group via readfirstlane
//  (forces scalar-load proof), 4 blocks/CU. Weights never touch VGPRs.
//  Predict: attn 493 -> ~75-110us, VALUBusy 39->80-90%, WRITE back ~2MB;
//  total 1149 -> ~700-750us.]

#define T_LEN 512
#define B_SZ  512
#define E_DIM 128
#define H_DIM 64
#define G3    192          // 3*H
#define V_SZ  50001
#define TWOH  128

// workspace offsets (in floats)
#define XGV_SZ (V_SZ * G3)                 // 9,600,192
#define HS_SZ  (T_LEN * B_SZ * H_DIM)      // 16,777,216
#define OFF_XGV_F 0
#define OFF_XGV_B (XGV_SZ)
#define OFF_HS_F  (2 * XGV_SZ)
#define OFF_HS_B  (2 * XGV_SZ + HS_SZ)
#define OFF_SC    (2 * XGV_SZ + 2 * HS_SZ) // scores [B][T]
// total ws: 53,016,960 floats = 212 MB

__device__ __forceinline__ float sigm(float x) {
    return 1.0f / (1.0f + __expf(-x));
}
__device__ __forceinline__ float tanh_fast(float x) {
    float ax = fminf(fabsf(x), 15.0f);
    float e  = __expf(2.0f * ax);
    float r  = 1.0f - 2.0f / (e + 1.0f);
    return copysignf(r, x);
}
__device__ __forceinline__ float rdlane_f(float v, int l) {
    return __uint_as_float(__builtin_amdgcn_readlane(__float_as_uint(v), l));
}
// Opaque register pin (r9 result: does NOT force residency; kept only in
// gru_scan to leave that kernel byte-identical while attn is attacked).
#define PIN(x) asm volatile("" : "+v"(x))

// ---------------------------------------------------------------------------
// Kernel A: xgv[v][g] = b_ih[g] + sum_e embed[v][e] * w_ih[g][e]  (per dir)
// block 256 = 4 waves; block covers 64 vocab rows; lane j owns gate columns
// {j, 64+j, 128+j}; wave s covers rows s+4k.
// ---------------------------------------------------------------------------
__global__ __launch_bounds__(256, 2) void xgv_kernel(
    const float* __restrict__ embed,
    const float* __restrict__ w_ih_f, const float* __restrict__ b_ih_f,
    const float* __restrict__ w_ih_b, const float* __restrict__ b_ih_b,
    float* __restrict__ ws)
{
    const int dir = blockIdx.y;
    const float* __restrict__ w_ih = dir ? w_ih_b : w_ih_f;
    const float* __restrict__ b_ih = dir ? b_ih_b : b_ih_f;
    float* __restrict__ xgv = ws + (dir ? OFF_XGV_B : OFF_XGV_F);
    const int v0 = blockIdx.x * 64;
    const int j  = threadIdx.x & 63;
    const int s  = threadIdx.x >> 6;

    float accr[16], accz[16], accn[16];
#pragma unroll
    for (int k = 0; k < 16; ++k) { accr[k] = 0.f; accz[k] = 0.f; accn[k] = 0.f; }

#pragma unroll 1
    for (int ec = 0; ec < 4; ++ec) {
        float wrc[32], wzc[32], wnc[32];
        const float4* wpr = (const float4*)(w_ih + (j      ) * 128 + ec * 32);
        const float4* wpz = (const float4*)(w_ih + (64  + j) * 128 + ec * 32);
        const float4* wpn = (const float4*)(w_ih + (128 + j) * 128 + ec * 32);
#pragma unroll
        for (int i = 0; i < 8; ++i) {
            float4 a = wpr[i];
            wrc[4*i+0] = a.x; wrc[4*i+1] = a.y; wrc[4*i+2] = a.z; wrc[4*i+3] = a.w;
            float4 b = wpz[i];
            wzc[4*i+0] = b.x; wzc[4*i+1] = b.y; wzc[4*i+2] = b.z; wzc[4*i+3] = b.w;
            float4 c = wpn[i];
            wnc[4*i+0] = c.x; wnc[4*i+1] = c.y; wnc[4*i+2] = c.z; wnc[4*i+3] = c.w;
        }
#pragma unroll
        for (int k = 0; k < 16; ++k) {
            const int v = v0 + s + 4 * k;
            if (v < V_SZ) {
                const float4* ep = (const float4*)(embed + v * 128 + ec * 32);
#pragma unroll
                for (int i = 0; i < 8; ++i) {
                    float4 e4 = ep[i];
                    accr[k] = fmaf(e4.x, wrc[4*i+0], accr[k]);
                    accr[k] = fmaf(e4.y, wrc[4*i+1], accr[k]);
                    accr[k] = fmaf(e4.z, wrc[4*i+2], accr[k]);
                    accr[k] = fmaf(e4.w, wrc[4*i+3], accr[k]);
                    accz[k] = fmaf(e4.x, wzc[4*i+0], accz[k]);
                    accz[k] = fmaf(e4.y, wzc[4*i+1], accz[k]);
                    accz[k] = fmaf(e4.z, wzc[4*i+2], accz[k]);
                    accz[k] = fmaf(e4.w, wzc[4*i+3], accz[k]);
                    accn[k] = fmaf(e4.x, wnc[4*i+0], accn[k]);
                    accn[k] = fmaf(e4.y, wnc[4*i+1], accn[k]);
                    accn[k] = fmaf(e4.z, wnc[4*i+2], accn[k]);
                    accn[k] = fmaf(e4.w, wnc[4*i+3], accn[k]);
                }
            }
        }
    }
    const float br = b_ih[j], bz = b_ih[64 + j], bn = b_ih[128 + j];
#pragma unroll
    for (int k = 0; k < 16; ++k) {
        const int v = v0 + s + 4 * k;
        if (v < V_SZ) {
            float* o = xgv + (size_t)v * G3;
            o[j]        = accr[k] + br;
            o[64 + j]   = accz[k] + bz;
            o[128 + j]  = accn[k] + bn;
        }
    }
}

// ---------------------------------------------------------------------------
// Kernel B: the sequential GRU scan. 1 wave = 1 (batch row, direction) for
// all T steps. Unchanged from r9 (clean A/B while attn is attacked; will be
// re-attacked from its own counters once it tops the profile).
// ---------------------------------------------------------------------------
#define GRU_STEP(hh)                                        \
    {                                                       \
        const float h0v = rdlane_f(h, (hh));                \
        const float h1v = rdlane_f(h, (hh) + 1);            \
        ar0 = fmaf(h0v, wr[(hh)],     ar0);                 \
        az0 = fmaf(h0v, wz[(hh)],     az0);                 \
        an0 = fmaf(h0v, wn[(hh)],     an0);                 \
        ar1 = fmaf(h1v, wr[(hh) + 1], ar1);                 \
        az1 = fmaf(h1v, wz[(hh) + 1], az1);                 \
        an1 = fmaf(h1v, wn[(hh) + 1], an1);                 \
    }

__global__ __launch_bounds__(64) __attribute__((amdgpu_waves_per_eu(1, 1)))
void gru_scan_kernel(
    const int*   __restrict__ input,
    const float* __restrict__ h0,
    const float* __restrict__ w_hh_f, const float* __restrict__ b_hh_f,
    const float* __restrict__ w_hh_b, const float* __restrict__ b_hh_b,
    float* __restrict__ ws, float* __restrict__ d_out)
{
    const int dir = blockIdx.y;
    const int j   = threadIdx.x & 63;
    const int b   = blockIdx.x;

    const float* __restrict__ w_hh = dir ? w_hh_b : w_hh_f;
    const float* __restrict__ b_hh = dir ? b_hh_b : b_hh_f;
    const float* __restrict__ xgv  = ws + (dir ? OFF_XGV_B : OFF_XGV_F);
    float* __restrict__ hs = ws + (dir ? OFF_HS_B : OFF_HS_F);

    float wr[64], wz[64], wn[64];
    {
        const float4* pr = (const float4*)(w_hh + (j      ) * 64);
        const float4* pz = (const float4*)(w_hh + (64  + j) * 64);
        const float4* pn = (const float4*)(w_hh + (128 + j) * 64);
#pragma unroll
        for (int i = 0; i < 16; ++i) {
            float4 a = pr[i];
            wr[4*i+0] = a.x; wr[4*i+1] = a.y; wr[4*i+2] = a.z; wr[4*i+3] = a.w;
            float4 bq = pz[i];
            wz[4*i+0] = bq.x; wz[4*i+1] = bq.y; wz[4*i+2] = bq.z; wz[4*i+3] = bq.w;
            float4 c = pn[i];
            wn[4*i+0] = c.x; wn[4*i+1] = c.y; wn[4*i+2] = c.z; wn[4*i+3] = c.w;
        }
    }
#pragma unroll
    for (int i = 0; i < 64; ++i) { PIN(wr[i]); PIN(wz[i]); PIN(wn[i]); }

    const float br = b_hh[j], bz = b_hh[64 + j], bn = b_hh[128 + j];

    float h = h0[dir * (B_SZ * H_DIM) + b * H_DIM + j];

    int tok0 = __builtin_amdgcn_readfirstlane(input[(dir ? (T_LEN - 1) : 0) * B_SZ + b]);
    int tok_next_raw = input[(dir ? (T_LEN - 2) : 1) * B_SZ + b];
    float xr = xgv[(size_t)tok0 * G3 + j];
    float xz = xgv[(size_t)tok0 * G3 + 64 + j];
    float xn = xgv[(size_t)tok0 * G3 + 128 + j];

    for (int t = 0; t < T_LEN; ++t) {
        int tok_pf_raw = 0;
        if (t + 2 < T_LEN) {
            const int te2 = dir ? (T_LEN - 3 - t) : (t + 2);
            tok_pf_raw = input[te2 * B_SZ + b];
        }
        float nxr = 0.f, nxz = 0.f, nxn = 0.f;
        if (t + 1 < T_LEN) {
            const int tn = __builtin_amdgcn_readfirstlane(tok_next_raw);
            nxr = xgv[(size_t)tn * G3 + j];
            nxz = xgv[(size_t)tn * G3 + 64 + j];
            nxn = xgv[(size_t)tn * G3 + 128 + j];
        }

        float ar0 = br,  az0 = bz,  an0 = bn;
        float ar1 = 0.f, az1 = 0.f, an1 = 0.f;
        GRU_STEP(0)  GRU_STEP(2)  GRU_STEP(4)  GRU_STEP(6)
        GRU_STEP(8)  GRU_STEP(10) GRU_STEP(12) GRU_STEP(14)
        GRU_STEP(16) GRU_STEP(18) GRU_STEP(20) GRU_STEP(22)
        GRU_STEP(24) GRU_STEP(26) GRU_STEP(28) GRU_STEP(30)
        GRU_STEP(32) GRU_STEP(34) GRU_STEP(36) GRU_STEP(38)
        GRU_STEP(40) GRU_STEP(42) GRU_STEP(44) GRU_STEP(46)
        GRU_STEP(48) GRU_STEP(50) GRU_STEP(52) GRU_STEP(54)
        GRU_STEP(56) GRU_STEP(58) GRU_STEP(60) GRU_STEP(62)
        const float hr = ar0 + ar1;
        const float hz = az0 + az1;
        const float hn = an0 + an1;

        const float rg = sigm(xr + hr);
        const float zg = sigm(xz + hz);
        const float ng = tanh_fast(xn + rg * hn);
        h = (1.0f - zg) * ng + zg * h;

        const int te = dir ? (T_LEN - 1 - t) : t;
        hs[(size_t)te * (B_SZ * H_DIM) + b * H_DIM + j] = h;

        xr = nxr; xz = nxz; xn = nxn;
        tok_next_raw = tok_pf_raw;
    }
    d_out[B_SZ * TWOH + dir * (B_SZ * H_DIM) + b * H_DIM + j] = h;
}

// ---------------------------------------------------------------------------
// Kernel C (r11 rewrite): scalar-pipe GEMM for attention scores.
// scores[b][t] = sum_k cw[k] * tanh(bias[k] + sum_h ht[h] * W[h][k]).
// Block 256 thr = 4 waves, 64 rows (one t-slice chunk). ht (64 rows x 128 h)
// staged in LDS with pad->129 (banks (l+h)%32, 2-way = free). Wave w owns
// k-group k0 = readfirstlane(w*32) -- readfirstlane makes k0 provably
// uniform so W/bias/cw reads compile to s_load (SGPR operands; v_fmac
// vdst, sgpr, vgpr). Lane l owns row l: acc[32] in VGPRs (~50 total -- no
// allocator pressure, sidesteps the r8/r9/r10 residency war entirely).
// Cross-wave 4-way reduce in LDS; lane store to sc[b][t].
// ---------------------------------------------------------------------------
__global__ __launch_bounds__(256, 4) void attn_scores_kernel(
    const float* __restrict__ word_weight, const float* __restrict__ word_bias,
    const float* __restrict__ context_weight, float* __restrict__ ws)
{
    const int tid = threadIdx.x;
    const int l   = tid & 63;       // row within block
    const int wv  = tid >> 6;       // wave = k-group
    const float* __restrict__ hs_f = ws + OFF_HS_F;
    const float* __restrict__ hs_b = ws + OFF_HS_B;
    float* __restrict__ sc = ws + OFF_SC;

    __shared__ float ht[64][129];   // 64 rows x 128 h, +1 pad
    __shared__ float part[4][64];

    const int r0 = blockIdx.x * 64;     // row r = t*512 + b; 64 rows, same t
    const int t  = r0 >> 9;
    const int b0 = r0 & 511;

    // stage 64 rows: fwd h=0..63, bwd h=64..127. Coalesced global reads;
    // LDS writes land on consecutive banks (conflict-free).
    {
        const float* __restrict__ srcf = hs_f + (size_t)t * (B_SZ * H_DIM) + b0 * H_DIM;
        const float* __restrict__ srcb = hs_b + (size_t)t * (B_SZ * H_DIM) + b0 * H_DIM;
#pragma unroll
        for (int i = 0; i < 16; ++i) {
            const int idx = tid + i * 256;          // 0..4095
            const int row = idx >> 6, hh = idx & 63;
            ht[row][hh]      = srcf[idx];
            ht[row][64 + hh] = srcb[idx];
        }
    }
    __syncthreads();

    const int k0 = __builtin_amdgcn_readfirstlane(wv * 32);

    float acc[32];
#pragma unroll
    for (int k = 0; k < 32; ++k) acc[k] = word_bias[k0 + k];

    // h-loop: lane-private ht[l][h] (VGPR) x 32 uniform W values (SGPR).
#pragma unroll 4
    for (int h = 0; h < 128; ++h) {
        const float hv = ht[l][h];
        const float* __restrict__ wrow = word_weight + h * 128 + k0;
#pragma unroll
        for (int k = 0; k < 32; ++k) acc[k] = fmaf(hv, wrow[k], acc[k]);
    }

    float p = 0.f;
#pragma unroll
    for (int k = 0; k < 32; ++k) p += tanh_fast(acc[k]) * context_weight[k0 + k];
    part[wv][l] = p;
    __syncthreads();

    if (wv == 0) {
        sc[(b0 + l) * T_LEN + t] =
            (part[0][l] + part[1][l]) + (part[2][l] + part[3][l]);
    }
}

// ---------------------------------------------------------------------------
// Kernel D (fused): per batch row b — softmax over t of sc[b][:], then
// s_i[b][k] = sum_t a[t] * ht[t][b][k].  Block 512 threads = 8 waves.
// ---------------------------------------------------------------------------
__global__ __launch_bounds__(512, 2) void softmax_wsum_kernel(
    const float* __restrict__ ws_c, float* __restrict__ d_out)
{
    const float* __restrict__ hs_f = ws_c + OFF_HS_F;
    const float* __restrict__ hs_b = ws_c + OFF_HS_B;
    const float* __restrict__ sc   = ws_c + OFF_SC;
    const int b   = blockIdx.x;
    const int tid = threadIdx.x;

    __shared__ float red[8];
    __shared__ float sa[T_LEN];
    __shared__ float psum[4][TWOH];

    // ---- phase 1: softmax over t ----
    {
        const int t = tid;
        const int w = t >> 6;
        float v = sc[b * 512 + t];

        float m = v;
#pragma unroll
        for (int off = 32; off >= 1; off >>= 1) m = fmaxf(m, __shfl_xor(m, off));
        if ((t & 63) == 0) red[w] = m;
        __syncthreads();
        float mm = red[0];
#pragma unroll
        for (int i = 1; i < 8; ++i) mm = fmaxf(mm, red[i]);
        __syncthreads();

        const float e = __expf(v - mm);
        float ssum = e;
#pragma unroll
        for (int off = 32; off >= 1; off >>= 1) ssum += __shfl_xor(ssum, off);
        if ((t & 63) == 0) red[w] = ssum;
        __syncthreads();
        float tot = 0.f;
#pragma unroll
        for (int i = 0; i < 8; ++i) tot += red[i];

        sa[t] = e / tot;
    }
    __syncthreads();

    // ---- phase 2: weighted sum over t ----
    {
        const int k = tid & 127;
        const int c = tid >> 7;             // t-chunk 0..3
        const float* __restrict__ src =
            ((k < 64) ? hs_f : hs_b) + (k & 63) + b * H_DIM;
        const int t0 = c * 128;

        float acc = 0.f, acc2 = 0.f;
#pragma unroll 8
        for (int t = 0; t < 128; t += 2) {
            acc  = fmaf(sa[t0 + t],     src[(size_t)(t0 + t)     * (B_SZ * H_DIM)], acc);
            acc2 = fmaf(sa[t0 + t + 1], src[(size_t)(t0 + t + 1) * (B_SZ * H_DIM)], acc2);
        }
        psum[c][k] = acc + acc2;
    }
    __syncthreads();
    if (tid < TWOH) {
        d_out[b * TWOH + tid] =
            (psum[0][tid] + psum[1][tid]) + (psum[2][tid] + psum[3][tid]);
    }
}

// ---------------------------------------------------------------------------
extern "C" void kernel_launch(void* const* d_in, const int* in_sizes, int n_in,
                              void* d_out, int out_size, void* d_ws, size_t ws_size,
                              hipStream_t stream)
{
    const int*   input  = (const int*)  d_in[0];
    const float* hidden = (const float*)d_in[1];
    const float* embed  = (const float*)d_in[2];
    const float* word_w = (const float*)d_in[3];
    const float* word_b = (const float*)d_in[4];
    const float* ctx_w  = (const float*)d_in[5];
    const float* w_ih_f = (const float*)d_in[6];
    const float* w_hh_f = (const float*)d_in[7];
    const float* b_ih_f = (const float*)d_in[8];
    const float* b_hh_f = (const float*)d_in[9];
    const float* w_ih_b = (const float*)d_in[10];
    const float* w_hh_b = (const float*)d_in[11];
    const float* b_ih_b = (const float*)d_in[12];
    const float* b_hh_b = (const float*)d_in[13];
    float* ws  = (float*)d_ws;
    float* out = (float*)d_out;

    // A: vocab-folded input projection, both directions
    xgv_kernel<<<dim3((V_SZ + 63) / 64, 2), 256, 0, stream>>>(
        embed, w_ih_f, b_ih_f, w_ih_b, b_ih_b, ws);
    // B: sequential scan, 1 wave per (row, dir)
    gru_scan_kernel<<<dim3(B_SZ, 2), 64, 0, stream>>>(
        input, hidden, w_hh_f, b_hh_f, w_hh_b, b_hh_b, ws, out);
    // C: attention scores (scalar-pipe GEMM, 64 rows/block, 4 waves)
    attn_scores_kernel<<<(T_LEN * B_SZ) / 64, 256, 0, stream>>>(
        word_w, word_b, ctx_w, ws);
    // D: fused softmax over time + weighted sum -> s_i
    softmax_wsum_kernel<<<B_SZ, 512, 0, stream>>>(ws, out);
}